// Round 3
// baseline (570.912 us; speedup 1.0000x reference)
//
#include <hip/hip_runtime.h>
#include <hip/hip_cooperative_groups.h>
#include <hip/hip_bf16.h>

namespace cg = cooperative_groups;

// M=K=N=8192. x:[M,K] fp32, weight:[N,K] fp32.
// y[m] = 0.75 * dot(x[m,:], colsum(weight))
//
// Single cooperative kernel, 256 blocks x 1024 threads (1 block/CU, 16 waves/CU):
//   phase 1: partial column-sums of weight -> ws (4 MB, no atomics)
//   phase 2: fold 128 partials -> wcs[K] (LDS tree reduce)
//   phase 3: per-row dot of x with wcs (wcs staged in LDS per block)

#define M_DIM 8192
#define K_DIM 8192
#define N_DIM 8192
#define K4    (K_DIM / 4)      // 2048 float4 columns
#define NBLK  256
#define NTHR  1024
#define ROWCHUNKS 128          // partial vectors
#define RPC   (N_DIM / ROWCHUNKS)  // 64 rows per chunk
#define ROWS_PER_BLK (M_DIM / NBLK)  // 32

__global__ __launch_bounds__(NTHR) void fused_kernel(
    const float* __restrict__ x, const float* __restrict__ w,
    float* __restrict__ partial, float* __restrict__ wcs,
    float* __restrict__ y) {
    cg::grid_group grid = cg::this_grid();
    const int tid = threadIdx.x;
    const int b = blockIdx.x;

    __shared__ float4 red[8][128];   // phase 2 (16 KB)
    __shared__ float4 swcs[K4];      // phase 3 (32 KB)

    // ---------- Phase 1: partial column-sums (coalesced, no atomics) ----------
    {
        const int g = b * NTHR + tid;            // 0 .. 262143
        const int col4 = g & (K4 - 1);           // float4-column
        const int rowchunk = g >> 11;            // 0 .. 127
        const float4* __restrict__ p =
            (const float4*)w + (size_t)(rowchunk * RPC) * K4 + col4;
        float4 acc = make_float4(0.f, 0.f, 0.f, 0.f);
        #pragma unroll 8
        for (int r = 0; r < RPC; ++r) {
            float4 v = p[(size_t)r * K4];
            acc.x += v.x; acc.y += v.y; acc.z += v.z; acc.w += v.w;
        }
        ((float4*)partial)[(size_t)rowchunk * K4 + col4] = acc;
    }
    grid.sync();

    // ---------- Phase 2: fold 128 partials -> wcs (block b owns 8 cols) ----------
    {
        const int j = tid >> 7;       // 0..7  column-within-block
        const int c = tid & 127;      // 0..127 partial index
        const int col4 = b * 8 + j;
        red[j][c] = ((const float4*)partial)[(size_t)c * K4 + col4];
        __syncthreads();
        #pragma unroll
        for (int s = 64; s > 0; s >>= 1) {
            if (c < s) {
                float4 a = red[j][c], bb = red[j][c + s];
                a.x += bb.x; a.y += bb.y; a.z += bb.z; a.w += bb.w;
                red[j][c] = a;
            }
            __syncthreads();
        }
        if (c == 0) ((float4*)wcs)[col4] = red[j][0];
    }
    grid.sync();

    // ---------- Phase 3: rowdot, wcs staged in LDS ----------
    {
        for (int i = tid; i < K4; i += NTHR)
            swcs[i] = ((const float4*)wcs)[i];
        __syncthreads();

        const int wave = tid >> 6, lane = tid & 63;
        #pragma unroll
        for (int rr = 0; rr < ROWS_PER_BLK / 16; ++rr) {   // 2 rows per wave
            const int row = b * ROWS_PER_BLK + wave * 2 + rr;
            const float4* __restrict__ x4 = (const float4*)x + (size_t)row * K4;
            float acc = 0.f;
            #pragma unroll 8
            for (int i = lane; i < K4; i += 64) {
                float4 a = x4[i];
                float4 bb = swcs[i];
                acc += a.x * bb.x + a.y * bb.y + a.z * bb.z + a.w * bb.w;
            }
            #pragma unroll
            for (int off = 32; off > 0; off >>= 1)
                acc += __shfl_down(acc, off, 64);
            if (lane == 0) y[row] = 0.75f * acc;
        }
    }
}

extern "C" void kernel_launch(void* const* d_in, const int* in_sizes, int n_in,
                              void* d_out, int out_size, void* d_ws, size_t ws_size,
                              hipStream_t stream) {
    const float* x = (const float*)d_in[0];   // [M, K]
    const float* w = (const float*)d_in[1];   // [N, K]
    float* y = (float*)d_out;                 // [M]

    float* partial = (float*)d_ws;                               // 4 MB
    float* wcs     = (float*)d_ws + (size_t)ROWCHUNKS * K_DIM;   // 32 KB

    void* args[] = {(void*)&x, (void*)&w, (void*)&partial, (void*)&wcs, (void*)&y};
    hipLaunchCooperativeKernel((void*)fused_kernel, dim3(NBLK), dim3(NTHR),
                               args, 0, stream);
}